// Round 8
// baseline (514.144 us; speedup 1.0000x reference)
//
#include <hip/hip_runtime.h>

// radius-graph edges, N=8192 points in 2D, periodic box L=1.
// d_out (fp32, concatenated):
//   [0 .. N*N)      dist[i][j] = || minimum_image(x[j] - x[i]) ||
//   [N*N .. 2*N*N)  within[i][j] = (dist < 0.1) && (i != j)  as 0.0/1.0
//
// Write-BW-bound: 536 MB of output stores; x (64 KB) cache-resident.
// History: r2 (4col, plain) 507us == r6 (8col contiguous, plain) 514us;
// r3 (8col interleaved + nontemporal) 719us — the regression was the
// HALF-LINE-per-instruction pattern under nt, not nt itself (untested alone).
// This rev: contiguous layout (every wave dwordx4 = dense 1KB, full 64B lines
// per instruction) + nontemporal stores to keep 536MB of write-once data out
// of L2. Clean A/B of nt on the good layout.

constexpr int   N  = 8192;
constexpr float R0 = 0.1f;

typedef float f32x4 __attribute__((ext_vector_type(4)));

__global__ __launch_bounds__(256)
void radiusgraph_kernel(const float* __restrict__ x,
                        float* __restrict__ dist,
                        float* __restrict__ mask) {
    const int i    = blockIdx.y;                 // row (uniform per block)
    const int jblk = blockIdx.x * 2048;          // 2048 cols per block

    // row point: block-uniform -> scalar loads
    const float xix = x[2 * (size_t)i];
    const float xiy = x[2 * (size_t)i + 1];

    const size_t rowbase = (size_t)i * N;

#pragma unroll
    for (int h = 0; h < 2; ++h) {
        const int j = jblk + h * 1024 + threadIdx.x * 4;   // wave-contiguous 4-col chunk

        // 4 consecutive float2 points = two dwordx4 loads (L1/L2-hit)
        const f32x4 a = *reinterpret_cast<const f32x4*>(x + 2 * (size_t)j);
        const f32x4 b = *reinterpret_cast<const f32x4*>(x + 2 * (size_t)j + 4);

        const float xs[4] = {a.x, a.z, b.x, b.z};
        const float ys[4] = {a.y, a.w, b.y, b.w};

        f32x4 dout, mout;
#pragma unroll
        for (int k = 0; k < 4; ++k) {
            float dx = xs[k] - xix;
            float dy = ys[k] - xiy;
            dx -= rintf(dx);      // minimum image, L=1 (v_rndne_f32 == jnp.round)
            dy -= rintf(dy);
            const float d = sqrtf(dx * dx + dy * dy);
            dout[k] = d;
            mout[k] = (d < R0 && (j + k) != i) ? 1.0f : 0.0f;
        }

        // dense wave-contiguous 1 KB bursts; nt = bypass L2 retention
        __builtin_nontemporal_store(dout, reinterpret_cast<f32x4*>(dist + rowbase + j));
        __builtin_nontemporal_store(mout, reinterpret_cast<f32x4*>(mask + rowbase + j));
    }
}

extern "C" void kernel_launch(void* const* d_in, const int* in_sizes, int n_in,
                              void* d_out, int out_size, void* d_ws, size_t ws_size,
                              hipStream_t stream) {
    const float* x = (const float*)d_in[0];
    float* out  = (float*)d_out;
    float* dist = out;
    float* mask = out + (size_t)N * N;

    dim3 grid(N / 2048, N);      // (4, 8192) blocks, 256 thr
    radiusgraph_kernel<<<grid, dim3(256), 0, stream>>>(x, dist, mask);
}